// Round 8
// baseline (99.054 us; speedup 1.0000x reference)
//
#include <hip/hip_runtime.h>

typedef __attribute__((ext_vector_type(8))) short bf16x8;
typedef __attribute__((ext_vector_type(4))) float f32x4;

#define NSEG 64
#define NROW 8192
#define WROW 21504
#define NBPP 576          // block slots per phase
#define T0   64           // phase-0 row tile (MFMA)
#define T12  16           // phase-1/2 row tile
#define PA   136          // bf16 pitch of A tile in LDS (272 B, 16B-aligned)
#define P1   196
#define P2   164

__device__ __forceinline__ unsigned short f2bf(float f) {
    unsigned u = __float_as_uint(f);
    u += 0x7fffu + ((u >> 16) & 1u);     // round-to-nearest-even
    return (unsigned short)(u >> 16);
}

// ---------- pre-pass: x0 -> bf16 (n,k); W0 -> bf16 W_T (g,o,k) ----------
__global__ __launch_bounds__(256) void prep_kernel(
    const float* __restrict__ x0, const float* __restrict__ w,
    unsigned short* __restrict__ x0b, unsigned short* __restrict__ wt)
{
    const int t = threadIdx.x;
    const int b = blockIdx.x;
    if (b < 1024) {
        // x0: 1M floats = 262144 float4; 1024 blocks x 256 threads x 1 float4
        int i = b * 256 + t;
        float4 v = ((const float4*)x0)[i];
        ushort4 o;
        o.x = f2bf(v.x); o.y = f2bf(v.y); o.z = f2bf(v.z); o.w = f2bf(v.w);
        *(ushort4*)(x0b + (size_t)i * 4) = o;
    } else {
        // W0 transpose for segment g: read w[g][k][o] (fp32, coalesced) -> LDS,
        // write wt[g][o][k] (bf16, coalesced along k)
        __shared__ float lw[128 * 132];
        const int g = b - 1024;
        const float* wseg = w + (size_t)g * WROW;
        #pragma unroll
        for (int i = 0; i < 16; ++i) {           // 4096 float4
            int idx = t + i * 256;
            int r = idx >> 5, c4 = (idx & 31) * 4;
            float4 v = *(const float4*)(wseg + (size_t)r * 128 + c4);
            *(float4*)(lw + r * 132 + c4) = v;
        }
        __syncthreads();
        unsigned short* wo = wt + (size_t)g * 16384;
        #pragma unroll
        for (int i = 0; i < 16; ++i) {           // 4096 ushort4
            int idx = t + i * 256;
            int o = idx >> 5, k0 = (idx & 31) * 4;
            ushort4 v;
            v.x = f2bf(lw[(k0 + 0) * 132 + o]);
            v.y = f2bf(lw[(k0 + 1) * 132 + o]);
            v.z = f2bf(lw[(k0 + 2) * 132 + o]);
            v.w = f2bf(lw[(k0 + 3) * 132 + o]);
            *(ushort4*)(wo + (size_t)o * 128 + k0) = v;
        }
    }
}

// ---------- main ----------
__global__ __launch_bounds__(256) void iil_kernel(
    const float* __restrict__ x1, const float* __restrict__ x2,
    const float* __restrict__ w, const int* __restrict__ counts,
    const unsigned short* __restrict__ x0b, const unsigned short* __restrict__ wt,
    float* __restrict__ y0, float* __restrict__ y1, float* __restrict__ y2)
{
    __shared__ __align__(16) unsigned short smem_u[T0 * PA];   // 17408 B
    __shared__ int sstart[NSEG + 1];
    __shared__ int t16s[NSEG + 1];
    __shared__ int t64s[NSEG + 1];

    const int t = threadIdx.x;

    if (t < NSEG) {
        int c = counts[t];
        int v = c;
        #pragma unroll
        for (int d = 1; d < NSEG; d <<= 1) {
            int u = __shfl_up(v, d, 64);
            if (t >= d) v += u;
        }
        sstart[t + 1] = v;
        int a = (c + 15) >> 4;
        #pragma unroll
        for (int d = 1; d < NSEG; d <<= 1) {
            int u = __shfl_up(a, d, 64);
            if (t >= d) a += u;
        }
        t16s[t + 1] = a;
        int b2 = (c + 63) >> 6;
        #pragma unroll
        for (int d = 1; d < NSEG; d <<= 1) {
            int u = __shfl_up(b2, d, 64);
            if (t >= d) b2 += u;
        }
        t64s[t + 1] = b2;
        if (t == 0) { sstart[0] = 0; t16s[0] = 0; t64s[0] = 0; }
    }
    __syncthreads();

    const int phase = blockIdx.x / NBPP;
    const int pb = blockIdx.x - phase * NBPP;
    const float4 z4 = make_float4(0.f, 0.f, 0.f, 0.f);
    float* sbuf = (float*)smem_u;

    if (phase == 0) {
        if (pb >= t64s[NSEG]) return;
        int lo = 0, hi = NSEG;
        while (hi - lo > 1) {
            int mid = (lo + hi) >> 1;
            if (t64s[mid] <= pb) lo = mid; else hi = mid;
        }
        const int g = lo;
        const int s = sstart[g] + (pb - t64s[g]) * T0;
        const int nr = min(T0, sstart[g + 1] - s);

        // ---- stage A (bf16 raw copy): 64 rows x 128 bf16 = 1024 x uint4 ----
        unsigned short* As = smem_u;
        {
            const uint4* src = (const uint4*)(x0b + (size_t)s * 128);  // 16 uint4 per row
            const uint4 zz = make_uint4(0u, 0u, 0u, 0u);
            #pragma unroll
            for (int i = 0; i < 4; ++i) {          // 1024 uint4
                int idx = t + i * 256;
                int r = idx >> 4, c8 = idx & 15;   // r in [0,64), c8 in [0,16)
                uint4 v = (r < nr) ? src[idx] : zz;
                *(uint4*)(As + r * PA + c8 * 8) = v;
            }
        }
        __syncthreads();

        // ---- MFMA: wave = (mp = w&1 -> M-tiles, np = w>>1 -> N-tiles) ----
        const int lane = t & 63;
        const int wv = t >> 6;
        const int l16 = lane & 15;
        const int quad = lane >> 4;
        const int mp = wv & 1;
        const int np = wv >> 1;

        f32x4 acc[2][4];
        #pragma unroll
        for (int mt = 0; mt < 2; ++mt)
            #pragma unroll
            for (int nt = 0; nt < 4; ++nt)
                acc[mt][nt] = (f32x4){0.f, 0.f, 0.f, 0.f};

        const unsigned short* Abase = As + ((2 * mp) * 16 + l16) * PA + quad * 8;
        const unsigned short* Bbase = wt + (size_t)g * 16384
                                    + (size_t)((4 * np) * 16 + l16) * 128 + quad * 8;

        #pragma unroll
        for (int ks = 0; ks < 4; ++ks) {
            const int ko = ks * 32;
            bf16x8 a0 = *(const bf16x8*)(Abase + ko);
            bf16x8 a1 = *(const bf16x8*)(Abase + 16 * PA + ko);
            #pragma unroll
            for (int nt = 0; nt < 4; ++nt) {
                bf16x8 bfr = *(const bf16x8*)(Bbase + (size_t)nt * 16 * 128 + ko);
                acc[0][nt] = __builtin_amdgcn_mfma_f32_16x16x32_bf16(a0, bfr, acc[0][nt], 0, 0, 0);
                acc[1][nt] = __builtin_amdgcn_mfma_f32_16x16x32_bf16(a1, bfr, acc[1][nt], 0, 0, 0);
            }
        }

        // ---- epilogue: C/D layout col=lane&15, row=quad*4+reg ----
        const float c0 = 0.011048543456039806f;  // 1/(8*sqrt(128))
        #pragma unroll
        for (int mt = 0; mt < 2; ++mt) {
            int rbase = (2 * mp + mt) * 16 + quad * 4;
            #pragma unroll
            for (int nt = 0; nt < 4; ++nt) {
                int col = (4 * np + nt) * 16 + l16;
                #pragma unroll
                for (int rg = 0; rg < 4; ++rg) {
                    int r = rbase + rg;
                    if (r < nr)
                        y0[(size_t)(s + r) * 128 + col] = acc[mt][nt][rg] * c0;
                }
            }
        }
    } else if (phase == 1) {
        if (pb >= t16s[NSEG]) return;
        int lo = 0, hi = NSEG;
        while (hi - lo > 1) {
            int mid = (lo + hi) >> 1;
            if (t16s[mid] <= pb) lo = mid; else hi = mid;
        }
        const int g = lo;
        const int s = sstart[g] + (pb - t16s[g]) * T12;
        const int nr = min(T12, sstart[g + 1] - s);
        const float* __restrict__ wseg = w + (size_t)g * WROW;

        float* sx1 = sbuf;
        const float4* g1 = (const float4*)x1 + (size_t)s * 48;
        #pragma unroll
        for (int i = 0; i < 3; ++i) {               // 768 float4
            int idx = t + i * 256;
            int r = idx / 48, c = idx - r * 48;
            float4 v = (r < nr) ? g1[idx] : z4;
            *(float4*)(sx1 + r * P1 + c * 4) = v;
        }
        __syncthreads();

        const int og = t & 15;
        const int r = t >> 4;
        const float* xrow = sx1 + r * P1;
        const float* wp = wseg + 16384 + og * 4;
        float acc[12];
        #pragma unroll
        for (int i = 0; i < 12; ++i) acc[i] = 0.f;
        #pragma unroll 2
        for (int kq = 0; kq < 16; ++kq) {
            float4 xq0 = *(const float4*)(xrow + 12 * kq + 0);
            float4 xq1 = *(const float4*)(xrow + 12 * kq + 4);
            float4 xq2 = *(const float4*)(xrow + 12 * kq + 8);
            float xf[12] = {xq0.x, xq0.y, xq0.z, xq0.w,
                            xq1.x, xq1.y, xq1.z, xq1.w,
                            xq2.x, xq2.y, xq2.z, xq2.w};
            #pragma unroll
            for (int kk = 0; kk < 4; ++kk) {
                float4 wv = *(const float4*)(wp + (size_t)(4 * kq + kk) * 64);
                #pragma unroll
                for (int oo = 0; oo < 4; ++oo) {
                    float wvo = (oo == 0) ? wv.x : (oo == 1) ? wv.y : (oo == 2) ? wv.z : wv.w;
                    acc[oo * 3 + 0] = fmaf(wvo, xf[kk * 3 + 0], acc[oo * 3 + 0]);
                    acc[oo * 3 + 1] = fmaf(wvo, xf[kk * 3 + 1], acc[oo * 3 + 1]);
                    acc[oo * 3 + 2] = fmaf(wvo, xf[kk * 3 + 2], acc[oo * 3 + 2]);
                }
            }
        }
        const float c1 = 0.015625f;      // 1/(8*8)
        if (r < nr) {
            float* yb = y1 + (size_t)(s + r) * 192 + og * 12;
            *(float4*)(yb + 0) = make_float4(acc[0] * c1, acc[1] * c1, acc[2] * c1, acc[3] * c1);
            *(float4*)(yb + 4) = make_float4(acc[4] * c1, acc[5] * c1, acc[6] * c1, acc[7] * c1);
            *(float4*)(yb + 8) = make_float4(acc[8] * c1, acc[9] * c1, acc[10] * c1, acc[11] * c1);
        }
    } else {
        if (pb >= t16s[NSEG]) return;
        int lo = 0, hi = NSEG;
        while (hi - lo > 1) {
            int mid = (lo + hi) >> 1;
            if (t16s[mid] <= pb) lo = mid; else hi = mid;
        }
        const int g = lo;
        const int s = sstart[g] + (pb - t16s[g]) * T12;
        const int nr = min(T12, sstart[g + 1] - s);
        const float* __restrict__ wseg = w + (size_t)g * WROW;

        float* sx2 = sbuf;
        const float4* g2 = (const float4*)x2 + (size_t)s * 40;
        #pragma unroll
        for (int i = 0; i < 3; ++i) {               // 640 float4
            int idx = t + i * 256;
            if (idx < 640) {
                int r = idx / 40, c = idx - r * 40;
                float4 v = (r < nr) ? g2[idx] : z4;
                *(float4*)(sx2 + r * P2 + c * 4) = v;
            }
        }
        __syncthreads();

        const int og = t & 15;
        const int r = t >> 4;
        const float* xrow = sx2 + r * P2;
        const float* wp = wseg + 20480 + og * 2;
        float acc[10];
        #pragma unroll
        for (int i = 0; i < 10; ++i) acc[i] = 0.f;
        #pragma unroll
        for (int kq = 0; kq < 8; ++kq) {
            float xf[20];
            #pragma unroll
            for (int j = 0; j < 5; ++j) {
                float4 v = *(const float4*)(xrow + 20 * kq + 4 * j);
                xf[4 * j + 0] = v.x; xf[4 * j + 1] = v.y; xf[4 * j + 2] = v.z; xf[4 * j + 3] = v.w;
            }
            #pragma unroll
            for (int kk = 0; kk < 4; ++kk) {
                float2 wv = *(const float2*)(wp + (size_t)(4 * kq + kk) * 32);
                #pragma unroll
                for (int i = 0; i < 5; ++i) {
                    acc[i]     = fmaf(wv.x, xf[5 * kk + i], acc[i]);
                    acc[5 + i] = fmaf(wv.y, xf[5 * kk + i], acc[5 + i]);
                }
            }
        }
        const float c2 = 0.022097086912079608f;  // 1/(8*sqrt(32))
        if (r < nr) {
            float* yb = y2 + (size_t)(s + r) * 160 + og * 10;
            #pragma unroll
            for (int i = 0; i < 5; ++i)
                *(float2*)(yb + 2 * i) = make_float2(acc[2 * i] * c2, acc[2 * i + 1] * c2);
        }
    }
}

extern "C" void kernel_launch(void* const* d_in, const int* in_sizes, int n_in,
                              void* d_out, int out_size, void* d_ws, size_t ws_size,
                              hipStream_t stream) {
    const float* x0 = (const float*)d_in[0];
    const float* x1 = (const float*)d_in[1];
    const float* x2 = (const float*)d_in[2];
    const float* w  = (const float*)d_in[3];
    const int* counts = (const int*)d_in[4];

    float* y0 = (float*)d_out;
    float* y1 = y0 + (size_t)NROW * 128;
    float* y2 = y1 + (size_t)NROW * 192;

    unsigned short* x0b = (unsigned short*)d_ws;                 // 2 MB
    unsigned short* wtp = x0b + (size_t)NROW * 128;              // 2 MB

    hipLaunchKernelGGL(prep_kernel, dim3(1024 + NSEG), dim3(256), 0, stream,
                       x0, w, x0b, wtp);
    hipLaunchKernelGGL(iil_kernel, dim3(3 * NBPP), dim3(256), 0, stream,
                       x1, x2, w, counts, x0b, wtp, y0, y1, y2);
}

// Round 9
// 98.526 us; speedup vs baseline: 1.0054x; 1.0054x over previous
//
#include <hip/hip_runtime.h>

typedef __attribute__((ext_vector_type(8))) short bf16x8;
typedef __attribute__((ext_vector_type(4))) float f32x4;

#define NSEG 64
#define NROW 8192
#define WROW 21504
#define NBPP 320          // >= sum ceil(cnt/32) <= 256+64
#define PA0  136          // LDS pitch phase0 (bf16)
#define PA1  72           // LDS pitch phase1
#define PA2  40           // LDS pitch phase2

__device__ __forceinline__ unsigned short f2bf(float f) {
    unsigned u = __float_as_uint(f);
    u += 0x7fffu + ((u >> 16) & 1u);     // round-to-nearest-even
    return (unsigned short)(u >> 16);
}

// ---------- pre-pass ----------
// blocks 0..1023      : x0 -> bf16 (n, k)                      [8192 x 128]
// blocks 1024..2047   : x1 -> bf16 (n, i*64+m)                 [8192 x 192]
// blocks 2048..3071   : x2 -> bf16 (n, i*32+m)                 [8192 x 160]
// blocks 3072..3135   : W0^T (g,o,k), W1^T (g,o,m), W2^T (g,o,m) bf16
__global__ __launch_bounds__(256) void prep_kernel(
    const float* __restrict__ x0, const float* __restrict__ x1, const float* __restrict__ x2,
    const float* __restrict__ w,
    unsigned short* __restrict__ x0b, unsigned short* __restrict__ x1b,
    unsigned short* __restrict__ x2b,
    unsigned short* __restrict__ w0t, unsigned short* __restrict__ w1t,
    unsigned short* __restrict__ w2t)
{
    const int t = threadIdx.x;
    const int b = blockIdx.x;
    if (b < 1024) {
        int i = b * 256 + t;
        float4 v = ((const float4*)x0)[i];
        ushort4 o;
        o.x = f2bf(v.x); o.y = f2bf(v.y); o.z = f2bf(v.z); o.w = f2bf(v.w);
        *(ushort4*)(x0b + (size_t)i * 4) = o;
    } else if (b < 2048) {
        // x1: 8 rows/block, 24 uint4 per row -> 192 threads
        if (t < 192) {
            int n = (b - 1024) * 8 + (t / 24);
            int j = t % 24;                       // out chunk: i=j/8, m0=(j%8)*8
            int i = j >> 3, m0 = (j & 7) * 8;
            const float* src = x1 + (size_t)n * 192;
            unsigned short us[8];
            #pragma unroll
            for (int u = 0; u < 8; ++u)
                us[u] = f2bf(src[(m0 + u) * 3 + i]);
            *(uint4*)(x1b + (size_t)n * 192 + j * 8) = *(uint4*)us;
        }
    } else if (b < 3072) {
        // x2: 8 rows/block, 20 uint4 per row -> 160 threads
        if (t < 160) {
            int n = (b - 2048) * 8 + (t / 20);
            int j = t % 20;                       // i=j/4, m0=(j%4)*8
            int i = j >> 2, m0 = (j & 3) * 8;
            const float* src = x2 + (size_t)n * 160;
            unsigned short us[8];
            #pragma unroll
            for (int u = 0; u < 8; ++u)
                us[u] = f2bf(src[(m0 + u) * 5 + i]);
            *(uint4*)(x2b + (size_t)n * 160 + j * 8) = *(uint4*)us;
        }
    } else {
        __shared__ float lw[128 * 132];
        const int g = b - 3072;
        const float* wseg = w + (size_t)g * WROW;
        // ---- W0 (128x128) ----
        #pragma unroll
        for (int i = 0; i < 16; ++i) {
            int idx = t + i * 256;
            int r = idx >> 5, c4 = (idx & 31) * 4;
            float4 v = *(const float4*)(wseg + (size_t)r * 128 + c4);
            *(float4*)(lw + r * 132 + c4) = v;
        }
        __syncthreads();
        {
            unsigned short* wo = w0t + (size_t)g * 16384;
            #pragma unroll
            for (int i = 0; i < 16; ++i) {
                int idx = t + i * 256;
                int o = idx >> 5, k0 = (idx & 31) * 4;
                ushort4 v;
                v.x = f2bf(lw[(k0 + 0) * 132 + o]);
                v.y = f2bf(lw[(k0 + 1) * 132 + o]);
                v.z = f2bf(lw[(k0 + 2) * 132 + o]);
                v.w = f2bf(lw[(k0 + 3) * 132 + o]);
                *(ushort4*)(wo + (size_t)o * 128 + k0) = v;
            }
        }
        __syncthreads();
        // ---- W1 (64x64) ----
        {
            const float* w1 = wseg + 16384;
            #pragma unroll
            for (int i = 0; i < 4; ++i) {          // 1024 float4
                int idx = t + i * 256;
                int m = idx >> 4, o4 = (idx & 15) * 4;
                float4 v = *(const float4*)(w1 + (size_t)m * 64 + o4);
                *(float4*)(lw + m * 68 + o4) = v;
            }
        }
        __syncthreads();
        {
            unsigned short* wo = w1t + (size_t)g * 4096;
            #pragma unroll
            for (int i = 0; i < 4; ++i) {          // 1024 ushort4
                int idx = t + i * 256;
                int o = idx >> 4, m0 = (idx & 15) * 4;
                ushort4 v;
                v.x = f2bf(lw[(m0 + 0) * 68 + o]);
                v.y = f2bf(lw[(m0 + 1) * 68 + o]);
                v.z = f2bf(lw[(m0 + 2) * 68 + o]);
                v.w = f2bf(lw[(m0 + 3) * 68 + o]);
                *(ushort4*)(wo + (size_t)o * 64 + m0) = v;
            }
        }
        __syncthreads();
        // ---- W2 (32x32) ----
        {
            const float* w2 = wseg + 20480;
            int idx = t;                            // 256 float4
            int m = idx >> 3, o4 = (idx & 7) * 4;
            float4 v = *(const float4*)(w2 + (size_t)m * 32 + o4);
            *(float4*)(lw + m * 36 + o4) = v;
        }
        __syncthreads();
        {
            unsigned short* wo = w2t + (size_t)g * 1024;
            int idx = t;                            // 256 ushort4
            int o = idx >> 3, m0 = (idx & 7) * 4;
            ushort4 v;
            v.x = f2bf(lw[(m0 + 0) * 36 + o]);
            v.y = f2bf(lw[(m0 + 1) * 36 + o]);
            v.z = f2bf(lw[(m0 + 2) * 36 + o]);
            v.w = f2bf(lw[(m0 + 3) * 36 + o]);
            *(ushort4*)(wo + (size_t)o * 32 + m0) = v;
        }
    }
}

// ---------- main: all three phases are segment-aligned MFMA GEMMs ----------
__global__ __launch_bounds__(256) void iil_kernel(
    const int* __restrict__ counts,
    const unsigned short* __restrict__ x0b, const unsigned short* __restrict__ x1b,
    const unsigned short* __restrict__ x2b,
    const unsigned short* __restrict__ w0t, const unsigned short* __restrict__ w1t,
    const unsigned short* __restrict__ w2t,
    float* __restrict__ y0, float* __restrict__ y1, float* __restrict__ y2)
{
    __shared__ __align__(16) unsigned short As[96 * PA1];   // 13824 B (union, max phase1)
    __shared__ int sstart[NSEG + 1];
    __shared__ int t32s[NSEG + 1];

    const int t = threadIdx.x;

    if (t < NSEG) {
        int c = counts[t];
        int v = c;
        #pragma unroll
        for (int d = 1; d < NSEG; d <<= 1) {
            int u = __shfl_up(v, d, 64);
            if (t >= d) v += u;
        }
        sstart[t + 1] = v;
        int a = (c + 31) >> 5;
        #pragma unroll
        for (int d = 1; d < NSEG; d <<= 1) {
            int u = __shfl_up(a, d, 64);
            if (t >= d) a += u;
        }
        t32s[t + 1] = a;
        if (t == 0) { sstart[0] = 0; t32s[0] = 0; }
    }
    __syncthreads();

    const int phase = blockIdx.x / NBPP;
    const int pb = blockIdx.x - phase * NBPP;
    if (pb >= t32s[NSEG]) return;

    int lo = 0, hi = NSEG;
    while (hi - lo > 1) {
        int mid = (lo + hi) >> 1;
        if (t32s[mid] <= pb) lo = mid; else hi = mid;
    }
    const int g = lo;
    const int s = sstart[g] + (pb - t32s[g]) * 32;
    const int nr = min(32, sstart[g + 1] - s);

    const int lane = t & 63;
    const int wv = t >> 6;
    const int l16 = lane & 15;
    const int quad = lane >> 4;
    const uint4 zz = make_uint4(0u, 0u, 0u, 0u);

    if (phase == 0) {
        // ---- A: 32 rows x 128 bf16, pitch PA0 ----
        {
            const uint4* src = (const uint4*)(x0b + (size_t)s * 128);  // 16/row
            #pragma unroll
            for (int i = 0; i < 2; ++i) {
                int idx = t + i * 256;                  // [0,512)
                int r = idx >> 4, c8 = idx & 15;
                uint4 v = (r < nr) ? src[idx] : zz;
                *(uint4*)(As + r * PA0 + c8 * 8) = v;
            }
        }
        __syncthreads();

        const int mt = wv & 1;           // M-tile (rows mt*16..)
        const int np = wv >> 1;          // col half: nt = np*4..np*4+3
        f32x4 acc[4];
        #pragma unroll
        for (int nt = 0; nt < 4; ++nt) acc[nt] = (f32x4){0.f, 0.f, 0.f, 0.f};

        const unsigned short* Ab = As + (mt * 16 + l16) * PA0 + quad * 8;
        const unsigned short* Bb = w0t + (size_t)g * 16384
                                 + (size_t)((np * 4) * 16 + l16) * 128 + quad * 8;
        #pragma unroll
        for (int ks = 0; ks < 4; ++ks) {
            bf16x8 a = *(const bf16x8*)(Ab + ks * 32);
            #pragma unroll
            for (int nt = 0; nt < 4; ++nt) {
                bf16x8 bf = *(const bf16x8*)(Bb + (size_t)nt * 2048 + ks * 32);
                acc[nt] = __builtin_amdgcn_mfma_f32_16x16x32_bf16(a, bf, acc[nt], 0, 0, 0);
            }
        }
        const float c0 = 0.011048543456039806f;  // 1/(8*sqrt(128))
        const int rbase = mt * 16 + quad * 4;
        #pragma unroll
        for (int nt = 0; nt < 4; ++nt) {
            int col = (np * 4 + nt) * 16 + l16;
            #pragma unroll
            for (int rg = 0; rg < 4; ++rg) {
                int r = rbase + rg;
                if (r < nr)
                    y0[(size_t)(s + r) * 128 + col] = acc[nt][rg] * c0;
            }
        }
    } else if (phase == 1) {
        // ---- A: 96 M-rows (nl*3+i) x 64 m, pitch PA1 ----
        {
            const uint4* src = (const uint4*)(x1b + (size_t)s * 192);  // 24/row
            #pragma unroll
            for (int i = 0; i < 3; ++i) {
                int idx = t + i * 256;                  // [0,768)
                int nl = idx / 24, j = idx % 24;
                int ii = j >> 3, m0 = (j & 7) * 8;
                uint4 v = (nl < nr) ? src[idx] : zz;
                *(uint4*)(As + (nl * 3 + ii) * PA1 + m0) = v;
            }
        }
        __syncthreads();

        const int nt = wv;               // wave per N-tile
        f32x4 acc[6];
        #pragma unroll
        for (int mt = 0; mt < 6; ++mt) acc[mt] = (f32x4){0.f, 0.f, 0.f, 0.f};

        const unsigned short* Bb = w1t + (size_t)g * 4096
                                 + (size_t)(nt * 16 + l16) * 64 + quad * 8;
        bf16x8 b0 = *(const bf16x8*)(Bb);
        bf16x8 b1 = *(const bf16x8*)(Bb + 32);
        #pragma unroll
        for (int mt = 0; mt < 6; ++mt) {
            const unsigned short* Ab = As + (mt * 16 + l16) * PA1 + quad * 8;
            bf16x8 a0 = *(const bf16x8*)(Ab);
            bf16x8 a1 = *(const bf16x8*)(Ab + 32);
            acc[mt] = __builtin_amdgcn_mfma_f32_16x16x32_bf16(a0, b0, acc[mt], 0, 0, 0);
            acc[mt] = __builtin_amdgcn_mfma_f32_16x16x32_bf16(a1, b1, acc[mt], 0, 0, 0);
        }
        const float c1 = 0.015625f;      // 1/(8*8)
        const int col = nt * 16 + l16;
        #pragma unroll
        for (int mt = 0; mt < 6; ++mt) {
            #pragma unroll
            for (int rg = 0; rg < 4; ++rg) {
                int R = mt * 16 + quad * 4 + rg;
                int nl = R / 3, ii = R - nl * 3;
                if (nl < nr)
                    y1[(size_t)(s + nl) * 192 + col * 3 + ii] = acc[mt][rg] * c1;
            }
        }
    } else {
        // ---- A: 160 M-rows (nl*5+i) x 32 m, pitch PA2 ----
        {
            const uint4* src = (const uint4*)(x2b + (size_t)s * 160);  // 20/row
            #pragma unroll
            for (int i = 0; i < 3; ++i) {
                int idx = t + i * 256;                  // [0,640)
                if (idx < 640) {
                    int nl = idx / 20, j = idx % 20;
                    int ii = j >> 2, m0 = (j & 3) * 8;
                    uint4 v = (nl < nr) ? src[idx] : zz;
                    *(uint4*)(As + (nl * 5 + ii) * PA2 + m0) = v;
                }
            }
        }
        __syncthreads();

        const int mh = wv & 1;           // M half: tiles mh*5..mh*5+4
        const int nt = wv >> 1;          // N-tile
        f32x4 acc[5];
        #pragma unroll
        for (int mt = 0; mt < 5; ++mt) acc[mt] = (f32x4){0.f, 0.f, 0.f, 0.f};

        const unsigned short* Bb = w2t + (size_t)g * 1024
                                 + (size_t)(nt * 16 + l16) * 32 + quad * 8;
        bf16x8 b0 = *(const bf16x8*)(Bb);
        #pragma unroll
        for (int mt = 0; mt < 5; ++mt) {
            const unsigned short* Ab = As + ((mh * 5 + mt) * 16 + l16) * PA2 + quad * 8;
            bf16x8 a0 = *(const bf16x8*)(Ab);
            acc[mt] = __builtin_amdgcn_mfma_f32_16x16x32_bf16(a0, b0, acc[mt], 0, 0, 0);
        }
        const float c2 = 0.022097086912079608f;  // 1/(8*sqrt(32))
        const int col = nt * 16 + l16;
        #pragma unroll
        for (int mt = 0; mt < 5; ++mt) {
            #pragma unroll
            for (int rg = 0; rg < 4; ++rg) {
                int R = (mh * 5 + mt) * 16 + quad * 4 + rg;
                int nl = R / 5, ii = R - nl * 5;
                if (nl < nr)
                    y2[(size_t)(s + nl) * 160 + col * 5 + ii] = acc[mt][rg] * c2;
            }
        }
    }
}

extern "C" void kernel_launch(void* const* d_in, const int* in_sizes, int n_in,
                              void* d_out, int out_size, void* d_ws, size_t ws_size,
                              hipStream_t stream) {
    const float* x0 = (const float*)d_in[0];
    const float* x1 = (const float*)d_in[1];
    const float* x2 = (const float*)d_in[2];
    const float* w  = (const float*)d_in[3];
    const int* counts = (const int*)d_in[4];

    float* y0 = (float*)d_out;
    float* y1 = y0 + (size_t)NROW * 128;
    float* y2 = y1 + (size_t)NROW * 192;

    unsigned short* x0b = (unsigned short*)d_ws;                     // 2 MB
    unsigned short* x1b = x0b + (size_t)NROW * 128;                  // 3 MB
    unsigned short* x2b = x1b + (size_t)NROW * 192;                  // 2.5 MB
    unsigned short* w0t = x2b + (size_t)NROW * 160;                  // 2 MB
    unsigned short* w1t = w0t + (size_t)NSEG * 16384;                // 0.5 MB
    unsigned short* w2t = w1t + (size_t)NSEG * 4096;                 // 0.125 MB

    hipLaunchKernelGGL(prep_kernel, dim3(3072 + NSEG), dim3(256), 0, stream,
                       x0, x1, x2, w, x0b, x1b, x2b, w0t, w1t, w2t);
    hipLaunchKernelGGL(iil_kernel, dim3(3 * NBPP), dim3(256), 0, stream,
                       counts, x0b, x1b, x2b, w0t, w1t, w2t, y0, y1, y2);
}